// Round 11
// baseline (2808.876 us; speedup 1.0000x reference)
//
#include <hip/hip_runtime.h>
#include <stdint.h>

#define BB 4
#define NN 16384
#define NPOINT 1024
#define NSAMPLE 32
#define CC 64
#define RADIUS2 0.00999999977648258209228515625f
#define BIGF 1.0e10f

#define FT 512     // threads per block (8 waves)
#define NPAIR 16   // fps point-pairs per thread (32 points/thread)
#define NCONS 128  // consumer blocks
#define NGRP 256   // 16-centroid groups (4096 centroids / 16)

typedef float f32x2 __attribute__((ext_vector_type(2)));

// ---------------- repack w1 (64x67) -> (64x68) padded, pad=0 ----------------
// Also zeroes the 4096 centroid-ready flags (workspace may be poisoned).
__global__ __launch_bounds__(256) void repack_w1(const float* __restrict__ w1,
                                                 float* __restrict__ w1p,
                                                 int* __restrict__ flags) {
    int t = threadIdx.x;
    for (int i = t; i < 64 * 68; i += 256) {
        int o = i / 68, c = i % 68;
        w1p[i] = (c < 67) ? w1[o * 67 + c] : 0.0f;
    }
    for (int i = t; i < BB * NPOINT; i += 256) flags[i] = 0;
}

// DPP-based argmax step (max value, min index on ties) — validated bit-exact.
template <int CTRL>
__device__ __forceinline__ void amax_step(float& v, int& i) {
    int nv = __builtin_amdgcn_update_dpp(__float_as_int(v), __float_as_int(v),
                                         CTRL, 0xf, 0xf, false);
    int ni = __builtin_amdgcn_update_dpp(i, i, CTRL, 0xf, 0xf, false);
    float fv = __int_as_float(nv);
    if (fv > v || (fv == v && ni < i)) { v = fv; i = ni; }
}
__device__ __forceinline__ void wave_amax(float& v, int& i) {
    amax_step<0x111>(v, i);  // row_shr:1
    amax_step<0x112>(v, i);  // row_shr:2
    amax_step<0x114>(v, i);  // row_shr:4
    amax_step<0x118>(v, i);  // row_shr:8
    amax_step<0x142>(v, i);  // row_bcast:15
    amax_step<0x143>(v, i);  // row_bcast:31  -> lane63 holds full wave result
}

// ---------------- fused producer-consumer kernel ----------------
// Blocks 0..3: EXACT R8 fps (best measured: 1730us) with the centroid stash
// replaced by a streamed global store + RELEASE flag per iteration (R3-vs-R4
// showed in-loop global stores cost ~nothing). Blocks 4..131: each owns two
// 16-centroid groups; ACQUIRE-spin on the group's last flag, then the EXACT
// existing ball-query (per-wave, early-exit, list kept in LDS -- nidx never
// goes to global) and the EXACT existing mlp (1 thread per (centroid,sample)).
// Group pairing (c, 255-c) gives every block at most ONE late group -> the 4
// final groups (i0=1008, one per batch) are done by 4 distinct blocks
// concurrently; post-fps tail ~= one group's bq+mlp.
// Deadlock-proofing (R5/R6 lessons): 131KB LDS => 1 block/CU; 132 blocks
// <= 256 CUs => ALL blocks co-resident regardless of dispatch order;
// producers never wait; consumer spins are bounded (2^18 polls + s_sleep ->
// terminates with garbage instead of hanging); flags zeroed by the preceding
// repack launch on every graph replay.
__global__ __launch_bounds__(FT, 2)
void uber_kernel(const float* xyz, const float* features,
                 float* new_xyz, float* out,
                 const float* __restrict__ w1p, const float* __restrict__ b1,
                 const float* __restrict__ w2, const float* __restrict__ b2,
                 const float* __restrict__ w3, const float* __restrict__ b3,
                 int* flags) {
    __shared__ float sx[NN];            // 64 KB (fps winner lookup)
    __shared__ float sy[NN];            // 64 KB
    __shared__ float2 svi[2][8];        // fps parity double-buffered (v, idx)
    __shared__ int slist[16][NSAMPLE];  // 2 KB (consumer neighbor lists)

    const int t = threadIdx.x;
    const int lane = t & 63;

    if (blockIdx.x < BB) {
        // ======================= FPS producer (R8 exact) ====================
        const int b = blockIdx.x;
        const int w = t >> 6;  // 0..7
        const float* xb = xyz + (size_t)b * NN * 3;

        f32x2 px[NPAIR], py[NPAIR], pz[NPAIR], dd[NPAIR];

        // load + transpose: pair k covers points g = 2*(k*FT+t) and g+1
#pragma unroll
        for (int k = 0; k < NPAIR; ++k) {
            const float* p = xb + (size_t)6 * (k * FT + t);
            f32x2 a = *(const f32x2*)(p + 0);
            f32x2 bq = *(const f32x2*)(p + 2);
            f32x2 c = *(const f32x2*)(p + 4);
            int g = 2 * (k * FT + t);
            px[k].x = a.x;  py[k].x = a.y;  pz[k].x = bq.x;
            px[k].y = bq.y; py[k].y = c.x;  pz[k].y = c.y;
            *(f32x2*)&sx[g] = px[k];   // LDS copies for winner lookup
            *(f32x2*)&sy[g] = py[k];
            dd[k].x = BIGF; dd[k].y = BIGF;
        }
        // one-time non-volatile anchor (R8's exact form)
#pragma unroll
        for (int k = 0; k < NPAIR; ++k)
            asm("" : "+v"(px[k]), "+v"(py[k]), "+v"(pz[k]));

        float cx = xb[0], cy = xb[1], cz = xb[2];
        __syncthreads();

        for (int i = 0; i < NPOINT; ++i) {
            if (t == 0) {  // stream centroid + release the ready flag
                float* o = new_xyz + ((size_t)b * NPOINT + i) * 3;
                o[0] = cx; o[1] = cy; o[2] = cz;
                __hip_atomic_store(&flags[b * NPOINT + i], 1,
                                   __ATOMIC_RELEASE, __HIP_MEMORY_SCOPE_AGENT);
            }
            if (i == NPOINT - 1) break;

            f32x2 c2x; c2x.x = cx; c2x.y = cx;
            f32x2 c2y; c2y.x = cy; c2y.y = cy;
            f32x2 c2z; c2z.x = cz; c2z.y = cz;

            // EXACT numpy semantics: sub; squares rounded individually; sum
            // (x^2+y^2)+z^2; min; exact max (no rounding).
            float mxx = -1.0f, mxy = -1.0f;
#pragma unroll
            for (int k = 0; k < NPAIR; ++k) {
                f32x2 dx = px[k] - c2x;
                f32x2 dy = py[k] - c2y;
                f32x2 dz = pz[k] - c2z;
                f32x2 m0 = dx * dx;
                f32x2 m1 = dy * dy;
                f32x2 m2 = dz * dz;
                f32x2 d  = (m0 + m1) + m2;
                dd[k].x = fminf(dd[k].x, d.x);
                dd[k].y = fminf(dd[k].y, d.y);
                mxx = fmaxf(mxx, dd[k].x);
                mxy = fmaxf(mxy, dd[k].y);
            }
            float bv = fmaxf(mxx, mxy);

            // first-occurrence index: descending overwrite scan (.y then .x)
            int bj = 0;
#pragma unroll
            for (int k = NPAIR - 1; k >= 0; --k) {
                if (dd[k].y == bv) bj = 2 * k + 1;
                if (dd[k].x == bv) bj = 2 * k;
            }
            int bi = (bj >> 1) * (2 * FT) + 2 * t + (bj & 1);

            wave_amax(bv, bi);
            if (lane == 63) svi[i & 1][w] = make_float2(bv, __int_as_float(bi));
            __syncthreads();

            float2 s = svi[i & 1][lane & 7];
            float v2 = s.x;
            int i2 = __float_as_int(s.y);
            amax_step<0x111>(v2, i2);  // row_shr:1
            amax_step<0x112>(v2, i2);  // row_shr:2
            amax_step<0x114>(v2, i2);  // row_shr:4
            int ixs = __builtin_amdgcn_readlane(i2, 63);

            cx = sx[ixs];
            cy = sy[ixs];
            cz = xb[ixs * 3 + 2];
        }
        return;
    }

    // ========================= consumer =====================================
    const int c = blockIdx.x - BB;         // 0..127
    int gA = c, gB = (NGRP - 1) - c;
    if ((gA & 63) > (gB & 63)) { int tq = gA; gA = gB; gB = tq; }  // early first

    for (int r = 0; r < 2; ++r) {
        const int g = (r == 0) ? gA : gB;
        const int base = g * 16;           // first cid of this group

        if (t == 0) {  // bounded acquire-spin on the group's LAST flag;
                       // release chain makes all 16 coords visible.
            int guard = 0;
            while (__hip_atomic_load(&flags[base + 15], __ATOMIC_ACQUIRE,
                                     __HIP_MEMORY_SCOPE_AGENT) == 0) {
                if (++guard > (1 << 18)) break;  // ~40ms cap: no hang, ever
                __builtin_amdgcn_s_sleep(2);
            }
        }
        __syncthreads();

        // ---- ball query (exact validated code): wave w does n=2w, 2w+1 ----
        const int w = t >> 6;
        for (int q = 0; q < 2; ++q) {
            const int n = 2 * w + q;
            const int cid = base + n;
            const int b_ = cid >> 10;
            const float* xb = xyz + (size_t)b_ * NN * 3;
            const float* cc = new_xyz + (size_t)cid * 3;
            float cx = cc[0], cy = cc[1], cz = cc[2];

            int cnt = 0;
            for (int bs = 0; bs < NN && cnt < NSAMPLE; bs += 64) {
                int j = bs + lane;
                float dx = __fsub_rn(xb[j * 3 + 0], cx);
                float dy = __fsub_rn(xb[j * 3 + 1], cy);
                float dz = __fsub_rn(xb[j * 3 + 2], cz);
                float d2 = __fadd_rn(__fadd_rn(__fmul_rn(dx, dx),
                                               __fmul_rn(dy, dy)),
                                     __fmul_rn(dz, dz));
                bool hit = d2 < RADIUS2;
                unsigned long long m = __ballot(hit);
                int pre = __popcll(m & ((1ull << lane) - 1ull));
                if (hit) {
                    int pos = cnt + pre;
                    if (pos < NSAMPLE) slist[n][pos] = j;
                }
                cnt += __popcll(m);  // uniform
            }
            if (lane < NSAMPLE) {  // pad in place (wave-ordered LDS ops)
                int first = slist[n][0];  // centroid itself always hits
                int v = (lane < cnt) ? slist[n][lane] : first;
                slist[n][lane] = v;
            }
        }
        __syncthreads();

        // ---- mlp (exact validated code): thread = (centroid n, sample s) ---
        {
            const int n = t >> 5;
            const int s = t & 31;
            const int cid = base + n;
            const int b_ = cid >> 10;
            const int p = cid & 1023;
            const int idx = slist[n][s];

            const float* nc = new_xyz + (size_t)cid * 3;
            const float* pt = xyz + ((size_t)b_ * NN + idx) * 3;
            float gx = pt[0] - nc[0], gy = pt[1] - nc[1], gz = pt[2] - nc[2];

            float fin[64];
            const float4* fp =
                (const float4*)(features + ((size_t)b_ * NN + idx) * CC);
#pragma unroll
            for (int j = 0; j < 16; ++j) {
                float4 q = fp[j];
                fin[4 * j] = q.x; fin[4 * j + 1] = q.y;
                fin[4 * j + 2] = q.z; fin[4 * j + 3] = q.w;
            }

            float h1[64];
#pragma unroll
            for (int o = 0; o < 64; ++o) {
                const float4* wr = (const float4*)(w1p + o * 68);
                float acc = b1[o];
                float4 q0 = wr[0];
                acc = fmaf(q0.x, gx, acc);
                acc = fmaf(q0.y, gy, acc);
                acc = fmaf(q0.z, gz, acc);
                acc = fmaf(q0.w, fin[0], acc);
#pragma unroll
                for (int j = 1; j < 17; ++j) {
                    float4 q = wr[j];
                    int c0 = 4 * j - 3;
                    acc = fmaf(q.x, fin[c0], acc);
                    acc = fmaf(q.y, fin[c0 + 1], acc);
                    acc = fmaf(q.z, fin[c0 + 2], acc);
                    if (c0 + 3 < 64) acc = fmaf(q.w, fin[c0 + 3], acc);
                }
                h1[o] = fmaxf(acc, 0.0f);
            }

            float h2[64];
#pragma unroll
            for (int o = 0; o < 64; ++o) {
                const float4* wr = (const float4*)(w2 + o * 64);
                float acc = b2[o];
#pragma unroll
                for (int j = 0; j < 16; ++j) {
                    float4 q = wr[j];
                    acc = fmaf(q.x, h1[4 * j], acc);
                    acc = fmaf(q.y, h1[4 * j + 1], acc);
                    acc = fmaf(q.z, h1[4 * j + 2], acc);
                    acc = fmaf(q.w, h1[4 * j + 3], acc);
                }
                h2[o] = fmaxf(acc, 0.0f);
            }

            float* ob = out + (size_t)b_ * 128 * NPOINT + p;
#pragma unroll
            for (int o = 0; o < 128; ++o) {
                const float4* wr = (const float4*)(w3 + o * 64);
                float acc = b3[o];
#pragma unroll
                for (int j = 0; j < 16; ++j) {
                    float4 q = wr[j];
                    acc = fmaf(q.x, h2[4 * j], acc);
                    acc = fmaf(q.y, h2[4 * j + 1], acc);
                    acc = fmaf(q.z, h2[4 * j + 2], acc);
                    acc = fmaf(q.w, h2[4 * j + 3], acc);
                }
                float r2 = fmaxf(acc, 0.0f);
#pragma unroll
                for (int off = 1; off < 32; off <<= 1) {
                    float orr = __shfl_xor(r2, off);
                    r2 = fmaxf(r2, orr);
                }
                if (s == 0) ob[(size_t)o * NPOINT] = r2;
            }
        }
        __syncthreads();  // slist reused next round
    }
}

extern "C" void kernel_launch(void* const* d_in, const int* in_sizes, int n_in,
                              void* d_out, int out_size, void* d_ws, size_t ws_size,
                              hipStream_t stream) {
    const float* xyz = (const float*)d_in[0];
    const float* features = (const float*)d_in[1];
    const float* w1 = (const float*)d_in[2];
    const float* b1 = (const float*)d_in[3];
    const float* w2 = (const float*)d_in[4];
    const float* b2 = (const float*)d_in[5];
    const float* w3 = (const float*)d_in[6];
    const float* b3 = (const float*)d_in[7];

    float* out = (float*)d_out;
    float* new_xyz = out;                          // B*NPOINT*3
    float* new_feat = out + BB * NPOINT * 3;       // B*128*NPOINT (base = out)

    float* w1p = (float*)d_ws;                                  // 64*68 floats
    int* flags = (int*)((char*)d_ws + 64 * 68 * sizeof(float)); // 4096 ints

    hipLaunchKernelGGL(repack_w1, dim3(1), dim3(256), 0, stream, w1, w1p, flags);
    hipLaunchKernelGGL(uber_kernel, dim3(BB + NCONS), dim3(FT), 0, stream,
                       xyz, features, new_xyz, out + BB * NPOINT * 3 - 0, // see note
                       w1p, b1, w2, b2, w3, b3, flags);
    (void)new_feat;
}

// Round 12
// 2315.462 us; speedup vs baseline: 1.2131x; 1.2131x over previous
//
#include <hip/hip_runtime.h>
#include <stdint.h>

#define BB 4
#define NN 16384
#define NPOINT 1024
#define NSAMPLE 32
#define CC 64
#define RADIUS2 0.00999999977648258209228515625f
#define BIGF 1.0e10f

#define FT 512     // threads per block (8 waves)
#define NPAIR 16   // fps point-pairs per thread (32 points/thread)
#define NCONS 128  // consumer blocks
#define NGRP 256   // 16-centroid groups (4096 centroids / 16)

typedef float f32x2 __attribute__((ext_vector_type(2)));

// ---------------- repack w1 (64x67) -> (64x68) padded, pad=0 ----------------
// Also zeroes the 256 group-ready flags (workspace may be poisoned).
__global__ __launch_bounds__(256) void repack_w1(const float* __restrict__ w1,
                                                 float* __restrict__ w1p,
                                                 int* __restrict__ flags) {
    int t = threadIdx.x;
    for (int i = t; i < 64 * 68; i += 256) {
        int o = i / 68, c = i % 68;
        w1p[i] = (c < 67) ? w1[o * 67 + c] : 0.0f;
    }
    flags[t] = 0;  // exactly NGRP entries
}

// DPP-based argmax step (max value, min index on ties) — validated bit-exact.
template <int CTRL>
__device__ __forceinline__ void amax_step(float& v, int& i) {
    int nv = __builtin_amdgcn_update_dpp(__float_as_int(v), __float_as_int(v),
                                         CTRL, 0xf, 0xf, false);
    int ni = __builtin_amdgcn_update_dpp(i, i, CTRL, 0xf, 0xf, false);
    float fv = __int_as_float(nv);
    if (fv > v || (fv == v && ni < i)) { v = fv; i = ni; }
}
__device__ __forceinline__ void wave_amax(float& v, int& i) {
    amax_step<0x111>(v, i);  // row_shr:1
    amax_step<0x112>(v, i);  // row_shr:2
    amax_step<0x114>(v, i);  // row_shr:4
    amax_step<0x118>(v, i);  // row_shr:8
    amax_step<0x142>(v, i);  // row_bcast:15
    amax_step<0x143>(v, i);  // row_bcast:31  -> lane63 holds full wave result
}

// ---------------- fused producer-consumer kernel ----------------
// R11 post-mortem: fusion was CORRECT but the producer slowed 1730->2750us
// from (a) per-iteration global store + RELEASE (the R4 barrier-drain tax,
// reintroduced) and (b) 128 consumers polling every ~50ns at AGENT scope
// (~40GB/s of coherent-point fetches; FETCH_SIZE 45->83MB).
// R12 removes both: producer hot loop is R8-EXACT (LDS stash only); every
// 16th iteration wave 0 flushes the group's 48 floats to new_xyz (coalesced)
// and RELEASEs ONE per-group flag -- vmcnt-drain paid 64x instead of 1024x.
// Consumers poll RELAXED at s_sleep(64) (~1.7us; groups arrive every ~27us)
// + one ACQUIRE load on detection. Co-residency: 133KB LDS => 1 block/CU,
// 132 blocks <= 256 CUs => all resident; producers never wait; consumer
// spins bounded (no hang possible); flags re-zeroed each replay by repack.
__global__ __launch_bounds__(FT, 2)
void uber_kernel(const float* xyz, const float* features,
                 float* new_xyz, float* out,
                 const float* __restrict__ w1p, const float* __restrict__ b1,
                 const float* __restrict__ w2, const float* __restrict__ b2,
                 const float* __restrict__ w3, const float* __restrict__ b3,
                 int* flags) {
    __shared__ float sx[NN];            // 64 KB (fps winner lookup)
    __shared__ float sy[NN];            // 64 KB
    __shared__ float2 svi[2][8];        // fps parity double-buffered (v, idx)
    __shared__ float stg[48];           // rolling 16-centroid stash
    __shared__ int slist[16][NSAMPLE];  // 2 KB (consumer neighbor lists)

    const int t = threadIdx.x;
    const int lane = t & 63;

    if (blockIdx.x < BB) {
        // ======================= FPS producer (R8 exact) ====================
        const int b = blockIdx.x;
        const int w = t >> 6;  // 0..7
        const float* xb = xyz + (size_t)b * NN * 3;

        f32x2 px[NPAIR], py[NPAIR], pz[NPAIR], dd[NPAIR];

        // load + transpose: pair k covers points g = 2*(k*FT+t) and g+1
#pragma unroll
        for (int k = 0; k < NPAIR; ++k) {
            const float* p = xb + (size_t)6 * (k * FT + t);
            f32x2 a = *(const f32x2*)(p + 0);
            f32x2 bq = *(const f32x2*)(p + 2);
            f32x2 c = *(const f32x2*)(p + 4);
            int g = 2 * (k * FT + t);
            px[k].x = a.x;  py[k].x = a.y;  pz[k].x = bq.x;
            px[k].y = bq.y; py[k].y = c.x;  pz[k].y = c.y;
            *(f32x2*)&sx[g] = px[k];   // LDS copies for winner lookup
            *(f32x2*)&sy[g] = py[k];
            dd[k].x = BIGF; dd[k].y = BIGF;
        }
        // one-time non-volatile anchor (R8's exact form)
#pragma unroll
        for (int k = 0; k < NPAIR; ++k)
            asm("" : "+v"(px[k]), "+v"(py[k]), "+v"(pz[k]));

        float cx = xb[0], cy = xb[1], cz = xb[2];
        __syncthreads();

        for (int i = 0; i < NPOINT; ++i) {
            if (t == 0) {  // stash into rolling LDS slot (cheap, as R8)
                int sl = 3 * (i & 15);
                stg[sl + 0] = cx; stg[sl + 1] = cy; stg[sl + 2] = cz;
            }
            if ((i & 15) == 15 && w == 0) {
                // flush the completed 16-centroid group + release its flag.
                // stash writes and these reads are same-wave DS ops: in-order.
                int g16 = i >> 4;
                if (lane < 48) {
                    float v = stg[lane];
                    new_xyz[((size_t)b * NPOINT + (size_t)g16 * 16) * 3 + lane] = v;
                }
                if (lane == 0)  // release waits this wave's vmem stores
                    __hip_atomic_store(&flags[b * 64 + g16], 1,
                                       __ATOMIC_RELEASE, __HIP_MEMORY_SCOPE_AGENT);
            }
            if (i == NPOINT - 1) break;

            f32x2 c2x; c2x.x = cx; c2x.y = cx;
            f32x2 c2y; c2y.x = cy; c2y.y = cy;
            f32x2 c2z; c2z.x = cz; c2z.y = cz;

            // EXACT numpy semantics: sub; squares rounded individually; sum
            // (x^2+y^2)+z^2; min; exact max (no rounding).
            float mxx = -1.0f, mxy = -1.0f;
#pragma unroll
            for (int k = 0; k < NPAIR; ++k) {
                f32x2 dx = px[k] - c2x;
                f32x2 dy = py[k] - c2y;
                f32x2 dz = pz[k] - c2z;
                f32x2 m0 = dx * dx;
                f32x2 m1 = dy * dy;
                f32x2 m2 = dz * dz;
                f32x2 d  = (m0 + m1) + m2;
                dd[k].x = fminf(dd[k].x, d.x);
                dd[k].y = fminf(dd[k].y, d.y);
                mxx = fmaxf(mxx, dd[k].x);
                mxy = fmaxf(mxy, dd[k].y);
            }
            float bv = fmaxf(mxx, mxy);

            // first-occurrence index: descending overwrite scan (.y then .x)
            int bj = 0;
#pragma unroll
            for (int k = NPAIR - 1; k >= 0; --k) {
                if (dd[k].y == bv) bj = 2 * k + 1;
                if (dd[k].x == bv) bj = 2 * k;
            }
            int bi = (bj >> 1) * (2 * FT) + 2 * t + (bj & 1);

            wave_amax(bv, bi);
            if (lane == 63) svi[i & 1][w] = make_float2(bv, __int_as_float(bi));
            __syncthreads();

            float2 s = svi[i & 1][lane & 7];
            float v2 = s.x;
            int i2 = __float_as_int(s.y);
            amax_step<0x111>(v2, i2);  // row_shr:1
            amax_step<0x112>(v2, i2);  // row_shr:2
            amax_step<0x114>(v2, i2);  // row_shr:4
            int ixs = __builtin_amdgcn_readlane(i2, 63);

            cx = sx[ixs];
            cy = sy[ixs];
            cz = xb[ixs * 3 + 2];
        }
        return;
    }

    // ========================= consumer =====================================
    const int c = blockIdx.x - BB;         // 0..127
    int gA = c, gB = (NGRP - 1) - c;
    if ((gA & 63) > (gB & 63)) { int tq = gA; gA = gB; gB = tq; }  // early first

    for (int r = 0; r < 2; ++r) {
        const int g = (r == 0) ? gA : gB;
        const int base = g * 16;           // first cid of this group

        if (t == 0) {  // gentle bounded spin: RELAXED polls ~1.7us apart,
                       // one ACQUIRE load on success for ordering.
            int guard = 0;
            while (__hip_atomic_load(&flags[g], __ATOMIC_RELAXED,
                                     __HIP_MEMORY_SCOPE_AGENT) == 0) {
                if (++guard > (1 << 14)) break;  // ~28ms cap: no hang, ever
                __builtin_amdgcn_s_sleep(64);
            }
            (void)__hip_atomic_load(&flags[g], __ATOMIC_ACQUIRE,
                                    __HIP_MEMORY_SCOPE_AGENT);
        }
        __syncthreads();

        // ---- ball query (exact validated code): wave w does n=2w, 2w+1 ----
        const int w = t >> 6;
        for (int q = 0; q < 2; ++q) {
            const int n = 2 * w + q;
            const int cid = base + n;
            const int b_ = cid >> 10;
            const float* xb = xyz + (size_t)b_ * NN * 3;
            const float* cc = new_xyz + (size_t)cid * 3;
            float cx = cc[0], cy = cc[1], cz = cc[2];

            int cnt = 0;
            for (int bs = 0; bs < NN && cnt < NSAMPLE; bs += 64) {
                int j = bs + lane;
                float dx = __fsub_rn(xb[j * 3 + 0], cx);
                float dy = __fsub_rn(xb[j * 3 + 1], cy);
                float dz = __fsub_rn(xb[j * 3 + 2], cz);
                float d2 = __fadd_rn(__fadd_rn(__fmul_rn(dx, dx),
                                               __fmul_rn(dy, dy)),
                                     __fmul_rn(dz, dz));
                bool hit = d2 < RADIUS2;
                unsigned long long m = __ballot(hit);
                int pre = __popcll(m & ((1ull << lane) - 1ull));
                if (hit) {
                    int pos = cnt + pre;
                    if (pos < NSAMPLE) slist[n][pos] = j;
                }
                cnt += __popcll(m);  // uniform
            }
            if (lane < NSAMPLE) {  // pad in place (same-wave DS ops, ordered)
                int first = slist[n][0];  // centroid itself always hits
                int v = (lane < cnt) ? slist[n][lane] : first;
                slist[n][lane] = v;
            }
        }
        __syncthreads();

        // ---- mlp (exact validated code): thread = (centroid n, sample s) ---
        {
            const int n = t >> 5;
            const int s = t & 31;
            const int cid = base + n;
            const int b_ = cid >> 10;
            const int p = cid & 1023;
            const int idx = slist[n][s];

            const float* nc = new_xyz + (size_t)cid * 3;
            const float* pt = xyz + ((size_t)b_ * NN + idx) * 3;
            float gx = pt[0] - nc[0], gy = pt[1] - nc[1], gz = pt[2] - nc[2];

            float fin[64];
            const float4* fp =
                (const float4*)(features + ((size_t)b_ * NN + idx) * CC);
#pragma unroll
            for (int j = 0; j < 16; ++j) {
                float4 q = fp[j];
                fin[4 * j] = q.x; fin[4 * j + 1] = q.y;
                fin[4 * j + 2] = q.z; fin[4 * j + 3] = q.w;
            }

            float h1[64];
#pragma unroll
            for (int o = 0; o < 64; ++o) {
                const float4* wr = (const float4*)(w1p + o * 68);
                float acc = b1[o];
                float4 q0 = wr[0];
                acc = fmaf(q0.x, gx, acc);
                acc = fmaf(q0.y, gy, acc);
                acc = fmaf(q0.z, gz, acc);
                acc = fmaf(q0.w, fin[0], acc);
#pragma unroll
                for (int j = 1; j < 17; ++j) {
                    float4 q = wr[j];
                    int c0 = 4 * j - 3;
                    acc = fmaf(q.x, fin[c0], acc);
                    acc = fmaf(q.y, fin[c0 + 1], acc);
                    acc = fmaf(q.z, fin[c0 + 2], acc);
                    if (c0 + 3 < 64) acc = fmaf(q.w, fin[c0 + 3], acc);
                }
                h1[o] = fmaxf(acc, 0.0f);
            }

            float h2[64];
#pragma unroll
            for (int o = 0; o < 64; ++o) {
                const float4* wr = (const float4*)(w2 + o * 64);
                float acc = b2[o];
#pragma unroll
                for (int j = 0; j < 16; ++j) {
                    float4 q = wr[j];
                    acc = fmaf(q.x, h1[4 * j], acc);
                    acc = fmaf(q.y, h1[4 * j + 1], acc);
                    acc = fmaf(q.z, h1[4 * j + 2], acc);
                    acc = fmaf(q.w, h1[4 * j + 3], acc);
                }
                h2[o] = fmaxf(acc, 0.0f);
            }

            float* ob = out + (size_t)b_ * 128 * NPOINT + p;
#pragma unroll
            for (int o = 0; o < 128; ++o) {
                const float4* wr = (const float4*)(w3 + o * 64);
                float acc = b3[o];
#pragma unroll
                for (int j = 0; j < 16; ++j) {
                    float4 q = wr[j];
                    acc = fmaf(q.x, h2[4 * j], acc);
                    acc = fmaf(q.y, h2[4 * j + 1], acc);
                    acc = fmaf(q.z, h2[4 * j + 2], acc);
                    acc = fmaf(q.w, h2[4 * j + 3], acc);
                }
                float r2 = fmaxf(acc, 0.0f);
#pragma unroll
                for (int off = 1; off < 32; off <<= 1) {
                    float orr = __shfl_xor(r2, off);
                    r2 = fmaxf(r2, orr);
                }
                if (s == 0) ob[(size_t)o * NPOINT] = r2;
            }
        }
        __syncthreads();  // slist reused next round
    }
}

extern "C" void kernel_launch(void* const* d_in, const int* in_sizes, int n_in,
                              void* d_out, int out_size, void* d_ws, size_t ws_size,
                              hipStream_t stream) {
    const float* xyz = (const float*)d_in[0];
    const float* features = (const float*)d_in[1];
    const float* w1 = (const float*)d_in[2];
    const float* b1 = (const float*)d_in[3];
    const float* w2 = (const float*)d_in[4];
    const float* b2 = (const float*)d_in[5];
    const float* w3 = (const float*)d_in[6];
    const float* b3 = (const float*)d_in[7];

    float* out = (float*)d_out;
    float* new_xyz = out;                          // B*NPOINT*3
    float* new_feat = out + BB * NPOINT * 3;       // B*128*NPOINT

    float* w1p = (float*)d_ws;                                  // 64*68 floats
    int* flags = (int*)((char*)d_ws + 64 * 68 * sizeof(float)); // 256 ints

    hipLaunchKernelGGL(repack_w1, dim3(1), dim3(256), 0, stream, w1, w1p, flags);
    hipLaunchKernelGGL(uber_kernel, dim3(BB + NCONS), dim3(FT), 0, stream,
                       xyz, features, new_xyz, new_feat,
                       w1p, b1, w2, b2, w3, b3, flags);
}